// Round 5
// baseline (158.083 us; speedup 1.0000x reference)
//
#include <hip/hip_runtime.h>
#include <stdint.h>
#include <math.h>

// RouterLinear: C[b,o] = bias[o] + sum_k W[o, idx[b,k]] * x[b,k]; top-64 per
// row (values desc, tie -> lower index); outputs vals (f32) then indices (as
// float). fp64 accumulation, k-ascending order -> bit-exact vs np float64.
//
// R5: gemm occupancy 16->32 waves/CU (1024-thr blocks, 1 b/thread, same 64 KB
// swizzled tile); fused stream packs 2 k's per int4 (1 global b128 / 2 k);
// topk hist transposed (HADDR) to kill 32-way chunk-scan bank conflicts.

#define NB    1024
#define NIN   4096
#define NOUT  4096
#define NK    64
#define NTOPK 64

__device__ __forceinline__ int SWZ(int i) { return i ^ ((i >> 3) & 7); }

// ---------------------------------------------------------------- pack ------
// fused[k2*1024 + b] = { SWZ(idx[b][2k2])*16, bits(x[b][2k2]),
//                        SWZ(idx[b][2k2+1])*16, bits(x[b][2k2+1]) }
__global__ __launch_bounds__(256) void pack_kernel(const float* __restrict__ x,
                                                   const int* __restrict__ idx,
                                                   int4* __restrict__ fused) {
    int tid = blockIdx.x * 256 + threadIdx.x;   // 32768 threads
    int k2 = tid >> 10;
    int b  = tid & 1023;
    int base = (b << 6) + (k2 << 1);
    int   i0 = idx[base],  i1 = idx[base + 1];
    float x0 = x[base],    x1 = x[base + 1];
    fused[tid] = make_int4(SWZ(i0) << 4, __float_as_int(x0),
                           SWZ(i1) << 4, __float_as_int(x1));
}

// ---------------------------------------------------------------- gemm ------
// Block bo owns W rows [bo*4, bo*4+4) in a swizzled-transposed 64 KB LDS tile.
// 1024 threads (16 waves), 1 b per thread -> 2 blocks/CU = 32 waves/CU.
__global__ __launch_bounds__(1024, 8) void gemm_kernel(const int4* __restrict__ fused,
                                                       const float* __restrict__ W,
                                                       const float* __restrict__ bias,
                                                       double* __restrict__ C) {
    __shared__ float4 Wt[NIN];   // 64 KB
    const int t  = threadIdx.x;
    const int o0 = blockIdx.x * 4;

    // Conflict-free staging: coalesced row loads, 4x4 register transpose,
    // swizzled b128 writes (lane j -> i=4j+c covers all 8 bank-groups evenly).
    {
        const float4* w0p = reinterpret_cast<const float4*>(W + (size_t)(o0 + 0) * NIN);
        const float4* w1p = reinterpret_cast<const float4*>(W + (size_t)(o0 + 1) * NIN);
        const float4* w2p = reinterpret_cast<const float4*>(W + (size_t)(o0 + 2) * NIN);
        const float4* w3p = reinterpret_cast<const float4*>(W + (size_t)(o0 + 3) * NIN);
        float4 r0 = w0p[t], r1 = w1p[t], r2 = w2p[t], r3 = w3p[t];
        int i0 = t << 2;
        Wt[SWZ(i0 + 0)] = make_float4(r0.x, r1.x, r2.x, r3.x);
        Wt[SWZ(i0 + 1)] = make_float4(r0.y, r1.y, r2.y, r3.y);
        Wt[SWZ(i0 + 2)] = make_float4(r0.z, r1.z, r2.z, r3.z);
        Wt[SWZ(i0 + 3)] = make_float4(r0.w, r1.w, r2.w, r3.w);
    }
    __syncthreads();

    double acc[4];
#pragma unroll
    for (int r = 0; r < 4; ++r) acc[r] = (double)bias[o0 + r];

    const int4* fp = fused + t;   // element k2*1024 + t

#pragma unroll 4
    for (int k2 = 0; k2 < NK / 2; ++k2) {
        int4 f = fp[k2 << 10];
        const float4 w0 = *reinterpret_cast<const float4*>(
            reinterpret_cast<const char*>(Wt) + f.x);
        const float4 w1 = *reinterpret_cast<const float4*>(
            reinterpret_cast<const char*>(Wt) + f.z);
        // k-ascending accumulation order (matches np float64 bit-exactly)
        double x0 = (double)__int_as_float(f.y);
        acc[0] += x0 * (double)w0.x; acc[1] += x0 * (double)w0.y;
        acc[2] += x0 * (double)w0.z; acc[3] += x0 * (double)w0.w;
        double x1 = (double)__int_as_float(f.w);
        acc[0] += x1 * (double)w1.x; acc[1] += x1 * (double)w1.y;
        acc[2] += x1 * (double)w1.z; acc[3] += x1 * (double)w1.w;
    }

    double2* dst = reinterpret_cast<double2*>(C + (size_t)t * NOUT + o0);
    dst[0] = make_double2(acc[0], acc[1]);
    dst[1] = make_double2(acc[2], acc[3]);
}

// ---------------------------------------------------------------- top-k -----
// Monotone fp32 key: double->float rounding preserves order, so the crossing
// bin over fp32 keys yields a superset of the true top-64; the exact fp64
// bitonic sort of candidates then matches np exactly.
__device__ __forceinline__ unsigned keyf(double d) {
    unsigned u = __float_as_uint((float)d);
    return (u & 0x80000000u) ? ~u : (u | 0x80000000u);
}
// Transposed hist layout: chunk scans (bin = t*16+q) become lane-consecutive.
__device__ __forceinline__ int HADDR(int bin) { return ((bin & 15) << 8) | (bin >> 4); }

__global__ __launch_bounds__(256) void topk_kernel(const double* __restrict__ C,
                                                   float* __restrict__ outv,
                                                   float* __restrict__ outi) {
    __shared__ unsigned hist[4096];    // 16 KB; bin = key>>20 (sign+exp8+mant3)
    __shared__ double   cval[1024];    // 8 KB
    __shared__ int      cidx[1024];    // 4 KB
    __shared__ unsigned part[256];     // 1 KB, chunk sums -> chunk suffixes
    __shared__ int      sBstar;
    __shared__ unsigned sCnt;

    const int t = threadIdx.x;
    const double2* row2 = reinterpret_cast<const double2*>(C + (size_t)blockIdx.x * NOUT);

    // Row into registers once: v[2q],v[2q+1] = row[q*512 + 2t .. +1] (b128).
    double v[16];
#pragma unroll
    for (int q = 0; q < 8; ++q) {
        double2 d = row2[q * 256 + t];
        v[2 * q] = d.x; v[2 * q + 1] = d.y;
    }

    for (int j = t; j < 4096; j += 256) hist[j] = 0u;
    if (t == 0) sCnt = 0u;
    __syncthreads();

#pragma unroll
    for (int q = 0; q < 16; ++q)
        atomicAdd(&hist[HADDR(keyf(v[q]) >> 20)], 1u);
    __syncthreads();

    // chunk sums (16 bins/chunk), conflict-free via HADDR transpose
    {
        unsigned s = 0;
#pragma unroll
        for (int q = 0; q < 16; ++q) s += hist[(q << 8) | t];
        part[t] = s;
    }
    __syncthreads();

    // single-wave suffix scan of the 256 chunk sums
    if (t < 64) {
        unsigned c0 = part[4 * t + 0], c1 = part[4 * t + 1];
        unsigned c2 = part[4 * t + 2], c3 = part[4 * t + 3];
        unsigned s = c0 + c1 + c2 + c3;
        unsigned suf = s;
        for (int off = 1; off < 64; off <<= 1) {
            unsigned xx = __shfl_down(suf, off);
            if (t + off < 64) suf += xx;
        }
        unsigned below = suf - s;           // sum of chunks > 4t+3
        part[4 * t + 3] = below + c3;
        part[4 * t + 2] = below + c3 + c2;
        part[4 * t + 1] = below + c3 + c2 + c1;
        part[4 * t + 0] = below + s;
    }
    __syncthreads();

    // crossing bin B*: max bin with count(key_bin >= B*) >= 64
    {
        unsigned run = (t < 255) ? part[t + 1] : 0u;
#pragma unroll
        for (int q = 15; q >= 0; --q) {
            unsigned cge = run + hist[(q << 8) | t];
            if (cge >= 64u && run < 64u) sBstar = t * 16 + q;
            run = cge;
        }
    }
    __syncthreads();

    const unsigned Bstar = (unsigned)sBstar;
#pragma unroll
    for (int q = 0; q < 16; ++q) {
        if ((keyf(v[q]) >> 20) >= Bstar) {
            unsigned pos = atomicAdd(&sCnt, 1u);
            if (pos < 1024u) {
                cval[pos] = v[q];
                cidx[pos] = (q >> 1) * 512 + 2 * t + (q & 1);
            }
        }
    }
    __syncthreads();

    int M = (int)sCnt; if (M > 1024) M = 1024;
    int n = 64; while (n < M) n <<= 1;
    for (int j = M + t; j < n; j += 256) { cval[j] = -INFINITY; cidx[j] = 0x7fffffff; }
    __syncthreads();

    // bitonic sort: value desc, index asc
    for (int kk = 2; kk <= n; kk <<= 1) {
        for (int jj = kk >> 1; jj > 0; jj >>= 1) {
            for (int i = t; i < n; i += 256) {
                int l = i ^ jj;
                if (l > i) {
                    double v1 = cval[i], v2 = cval[l];
                    int    i1 = cidx[i], i2 = cidx[l];
                    bool first = (v1 > v2) || (v1 == v2 && i1 < i2);
                    bool asc   = ((i & kk) == 0);
                    if (first != asc) {
                        cval[i] = v2; cval[l] = v1;
                        cidx[i] = i2; cidx[l] = i1;
                    }
                }
            }
            __syncthreads();
        }
    }

    if (t < 64) {
        outv[(blockIdx.x << 6) + t] = (float)cval[t];
        outi[(blockIdx.x << 6) + t] = (float)cidx[t];
    }
}

// ---------------------------------------------------------------- launch ----
extern "C" void kernel_launch(void* const* d_in, const int* in_sizes, int n_in,
                              void* d_out, int out_size, void* d_ws, size_t ws_size,
                              hipStream_t stream) {
    const float* x    = (const float*)d_in[0];
    const float* W    = (const float*)d_in[1];
    const float* bias = (const float*)d_in[2];
    const int*   idx  = (const int*)d_in[3];

    char*   ws    = (char*)d_ws;
    double* C     = (double*)ws;                                       // 32 MB
    int4*   fused = (int4*)(ws + (size_t)NB * NOUT * sizeof(double));  // 512 KB

    float* outv = (float*)d_out;
    float* outi = outv + NB * NTOPK;

    pack_kernel<<<(NB * NK / 2) / 256, 256, 0, stream>>>(x, idx, fused);
    gemm_kernel<<<NOUT / 4, 1024, 0, stream>>>(fused, W, bias, C);
    topk_kernel<<<NB, 256, 0, stream>>>(C, outv, outi);
}

// Round 6
// 155.797 us; speedup vs baseline: 1.0147x; 1.0147x over previous
//
#include <hip/hip_runtime.h>
#include <stdint.h>
#include <math.h>

// RouterLinear: C[b,o] = bias[o] + sum_k W[o, idx[b,k]] * x[b,k]; top-64 per
// row (values desc, tie -> lower index); outputs vals (f32) then indices (as
// float). fp64 accumulation -> ranking matches np float64 (absmax 0 in R1-R5).
//
// R6: gemm is LDS-pipe-bound (35 us of 57 is ds_read+conflicts; W already read
// from HBM exactly once; gather traffic 1.07 GB is intrinsic). This round cuts
// the one compressible input: the per-(b,k) stream. Swizzled LDS byte offset
// fits in 16 bits -> offs8 (uint4 = 8 k's) + xs4 (float4 = 4 k's): 3 global
// b128 per 8 k instead of 4; L2 stream 512->384 MB.

#define NB    1024
#define NIN   4096
#define NOUT  4096
#define NK    64
#define NTOPK 64

__device__ __forceinline__ int SWZ(int i) { return i ^ ((i >> 3) & 7); }

// ---------------------------------------------------------------- pack ------
// offs8[k8*1024 + b] : uint4 = 8 packed ushorts  (SWZ(idx[b][8k8+j])<<4)
// xs4 [k4*1024 + b]  : float4 = x[b][4k4 .. 4k4+3]
__global__ __launch_bounds__(256) void pack_kernel(const float* __restrict__ x,
                                                   const int* __restrict__ idx,
                                                   uint4* __restrict__ offs8,
                                                   float4* __restrict__ xs4) {
    int tid = blockIdx.x * 256 + threadIdx.x;   // 8192 threads: (b, k8)
    int b  = tid >> 3;
    int k8 = tid & 7;
    const int4* ip = reinterpret_cast<const int4*>(idx + (b << 6) + (k8 << 3));
    const float4* xp = reinterpret_cast<const float4*>(x + (b << 6) + (k8 << 3));
    int4 ia = ip[0], ib = ip[1];
    float4 xa = xp[0], xb = xp[1];

    unsigned o0 = (unsigned)(SWZ(ia.x) << 4), o1 = (unsigned)(SWZ(ia.y) << 4);
    unsigned o2 = (unsigned)(SWZ(ia.z) << 4), o3 = (unsigned)(SWZ(ia.w) << 4);
    unsigned o4 = (unsigned)(SWZ(ib.x) << 4), o5 = (unsigned)(SWZ(ib.y) << 4);
    unsigned o6 = (unsigned)(SWZ(ib.z) << 4), o7 = (unsigned)(SWZ(ib.w) << 4);

    offs8[(k8 << 10) + b] = make_uint4(o0 | (o1 << 16), o2 | (o3 << 16),
                                       o4 | (o5 << 16), o6 | (o7 << 16));
    xs4[((k8 << 1) + 0) * 1024 + b] = xa;
    xs4[((k8 << 1) + 1) * 1024 + b] = xb;
}

// ---------------------------------------------------------------- gemm ------
// Block bo owns W rows [bo*4, bo*4+4) in a swizzled-transposed 64 KB LDS tile
// (conflict-free staging; gathers spread over all 8 bank-groups). 1024 threads,
// 1 b each, 2 blocks/CU.
__global__ __launch_bounds__(1024, 8) void gemm_kernel(const uint4* __restrict__ offs8,
                                                       const float4* __restrict__ xs4,
                                                       const float* __restrict__ W,
                                                       const float* __restrict__ bias,
                                                       double* __restrict__ C) {
    __shared__ float4 Wt[NIN];   // 64 KB
    const int t  = threadIdx.x;
    const int o0 = blockIdx.x * 4;

    // Conflict-free staging: coalesced row loads, 4x4 register transpose,
    // swizzled b128 writes (lane j -> i=4j+c covers all 8 bank-groups evenly).
    {
        const float4* w0p = reinterpret_cast<const float4*>(W + (size_t)(o0 + 0) * NIN);
        const float4* w1p = reinterpret_cast<const float4*>(W + (size_t)(o0 + 1) * NIN);
        const float4* w2p = reinterpret_cast<const float4*>(W + (size_t)(o0 + 2) * NIN);
        const float4* w3p = reinterpret_cast<const float4*>(W + (size_t)(o0 + 3) * NIN);
        float4 r0 = w0p[t], r1 = w1p[t], r2 = w2p[t], r3 = w3p[t];
        int i0 = t << 2;
        Wt[SWZ(i0 + 0)] = make_float4(r0.x, r1.x, r2.x, r3.x);
        Wt[SWZ(i0 + 1)] = make_float4(r0.y, r1.y, r2.y, r3.y);
        Wt[SWZ(i0 + 2)] = make_float4(r0.z, r1.z, r2.z, r3.z);
        Wt[SWZ(i0 + 3)] = make_float4(r0.w, r1.w, r2.w, r3.w);
    }
    __syncthreads();

    double acc[4];
#pragma unroll
    for (int r = 0; r < 4; ++r) acc[r] = (double)bias[o0 + r];

    const uint4*  op = offs8 + t;   // element k8*1024 + t
    const float4* xp = xs4 + t;     // element k4*1024 + t
    const char*   base = reinterpret_cast<const char*>(Wt);

#define GSTEP(OFF, XV)                                                        \
    {                                                                         \
        const float4 w = *reinterpret_cast<const float4*>(base + (OFF));      \
        double xd = (double)(XV);                                             \
        acc[0] += xd * (double)w.x; acc[1] += xd * (double)w.y;               \
        acc[2] += xd * (double)w.z; acc[3] += xd * (double)w.w;               \
    }

#pragma unroll 2
    for (int k8 = 0; k8 < NK / 8; ++k8) {
        uint4  o8 = op[k8 << 10];
        float4 xA = xp[(k8 << 11)];
        float4 xB = xp[(k8 << 11) + 1024];
        GSTEP(o8.x & 0xFFFFu, xA.x)
        GSTEP(o8.x >> 16,     xA.y)
        GSTEP(o8.y & 0xFFFFu, xA.z)
        GSTEP(o8.y >> 16,     xA.w)
        GSTEP(o8.z & 0xFFFFu, xB.x)
        GSTEP(o8.z >> 16,     xB.y)
        GSTEP(o8.w & 0xFFFFu, xB.z)
        GSTEP(o8.w >> 16,     xB.w)
    }
#undef GSTEP

    double2* dst = reinterpret_cast<double2*>(C + (size_t)t * NOUT + o0);
    dst[0] = make_double2(acc[0], acc[1]);
    dst[1] = make_double2(acc[2], acc[3]);
}

// ---------------------------------------------------------------- top-k -----
// Monotone fp32 key: double->float rounding preserves order, so the crossing
// bin over fp32 keys yields a superset of the true top-64; the exact fp64
// bitonic sort of candidates then matches np exactly.
__device__ __forceinline__ unsigned keyf(double d) {
    unsigned u = __float_as_uint((float)d);
    return (u & 0x80000000u) ? ~u : (u | 0x80000000u);
}
// Transposed hist layout: chunk scans (bin = t*16+q) become lane-consecutive.
__device__ __forceinline__ int HADDR(int bin) { return ((bin & 15) << 8) | (bin >> 4); }

__global__ __launch_bounds__(256) void topk_kernel(const double* __restrict__ C,
                                                   float* __restrict__ outv,
                                                   float* __restrict__ outi) {
    __shared__ unsigned hist[4096];    // 16 KB; bin = key>>20 (sign+exp8+mant3)
    __shared__ double   cval[1024];    // 8 KB
    __shared__ int      cidx[1024];    // 4 KB
    __shared__ unsigned part[256];     // 1 KB, chunk sums -> chunk suffixes
    __shared__ int      sBstar;
    __shared__ unsigned sCnt;

    const int t = threadIdx.x;
    const double2* row2 = reinterpret_cast<const double2*>(C + (size_t)blockIdx.x * NOUT);

    double v[16];
#pragma unroll
    for (int q = 0; q < 8; ++q) {
        double2 d = row2[q * 256 + t];
        v[2 * q] = d.x; v[2 * q + 1] = d.y;
    }

    for (int j = t; j < 4096; j += 256) hist[j] = 0u;
    if (t == 0) sCnt = 0u;
    __syncthreads();

#pragma unroll
    for (int q = 0; q < 16; ++q)
        atomicAdd(&hist[HADDR(keyf(v[q]) >> 20)], 1u);
    __syncthreads();

    {
        unsigned s = 0;
#pragma unroll
        for (int q = 0; q < 16; ++q) s += hist[(q << 8) | t];
        part[t] = s;
    }
    __syncthreads();

    if (t < 64) {
        unsigned c0 = part[4 * t + 0], c1 = part[4 * t + 1];
        unsigned c2 = part[4 * t + 2], c3 = part[4 * t + 3];
        unsigned s = c0 + c1 + c2 + c3;
        unsigned suf = s;
        for (int off = 1; off < 64; off <<= 1) {
            unsigned xx = __shfl_down(suf, off);
            if (t + off < 64) suf += xx;
        }
        unsigned below = suf - s;           // sum of chunks > 4t+3
        part[4 * t + 3] = below + c3;
        part[4 * t + 2] = below + c3 + c2;
        part[4 * t + 1] = below + c3 + c2 + c1;
        part[4 * t + 0] = below + s;
    }
    __syncthreads();

    {
        unsigned run = (t < 255) ? part[t + 1] : 0u;
#pragma unroll
        for (int q = 15; q >= 0; --q) {
            unsigned cge = run + hist[(q << 8) | t];
            if (cge >= 64u && run < 64u) sBstar = t * 16 + q;
            run = cge;
        }
    }
    __syncthreads();

    const unsigned Bstar = (unsigned)sBstar;
#pragma unroll
    for (int q = 0; q < 16; ++q) {
        if ((keyf(v[q]) >> 20) >= Bstar) {
            unsigned pos = atomicAdd(&sCnt, 1u);
            if (pos < 1024u) {
                cval[pos] = v[q];
                cidx[pos] = (q >> 1) * 512 + 2 * t + (q & 1);
            }
        }
    }
    __syncthreads();

    int M = (int)sCnt; if (M > 1024) M = 1024;
    int n = 64; while (n < M) n <<= 1;
    for (int j = M + t; j < n; j += 256) { cval[j] = -INFINITY; cidx[j] = 0x7fffffff; }
    __syncthreads();

    for (int kk = 2; kk <= n; kk <<= 1) {
        for (int jj = kk >> 1; jj > 0; jj >>= 1) {
            for (int i = t; i < n; i += 256) {
                int l = i ^ jj;
                if (l > i) {
                    double v1 = cval[i], v2 = cval[l];
                    int    i1 = cidx[i], i2 = cidx[l];
                    bool first = (v1 > v2) || (v1 == v2 && i1 < i2);
                    bool asc   = ((i & kk) == 0);
                    if (first != asc) {
                        cval[i] = v2; cval[l] = v1;
                        cidx[i] = i2; cidx[l] = i1;
                    }
                }
            }
            __syncthreads();
        }
    }

    if (t < 64) {
        outv[(blockIdx.x << 6) + t] = (float)cval[t];
        outi[(blockIdx.x << 6) + t] = (float)cidx[t];
    }
}

// ---------------------------------------------------------------- launch ----
extern "C" void kernel_launch(void* const* d_in, const int* in_sizes, int n_in,
                              void* d_out, int out_size, void* d_ws, size_t ws_size,
                              hipStream_t stream) {
    const float* x    = (const float*)d_in[0];
    const float* W    = (const float*)d_in[1];
    const float* bias = (const float*)d_in[2];
    const int*   idx  = (const int*)d_in[3];

    char*   ws    = (char*)d_ws;
    double* C     = (double*)ws;                                   // 32 MB
    uint4*  offs8 = (uint4*)(ws + (size_t)NB * NOUT * sizeof(double));          // 128 KB
    float4* xs4   = (float4*)(ws + (size_t)NB * NOUT * sizeof(double) + 131072); // 256 KB

    float* outv = (float*)d_out;
    float* outi = outv + NB * NTOPK;

    pack_kernel<<<(NB * 8) / 256, 256, 0, stream>>>(x, idx, offs8, xs4);
    gemm_kernel<<<NOUT / 4, 1024, 0, stream>>>(offs8, xs4, W, bias, C);
    topk_kernel<<<NB, 256, 0, stream>>>(C, outv, outi);
}

// Round 7
// 148.495 us; speedup vs baseline: 1.0646x; 1.0492x over previous
//
#include <hip/hip_runtime.h>
#include <stdint.h>
#include <math.h>

// RouterLinear: C[b,o] = bias[o] + sum_k W[o, idx[b,k]] * x[b,k]; top-64 per
// row (values desc, tie -> lower index); outputs vals (f32) then indices (as
// float). fp64 accumulation, k-ascending -> matches np float64 (absmax 0).
//
// R7: gemm software pipeline. LDS-pipe floor is ~34.6 us/CU (4096 wave b128
// gathers + 34k conflict cyc); R6 measured 52.5 with nothing saturated ->
// scheduling slack. This round: rotate next-k8 stream loads ahead of consume,
// batch gathers 4-wide before cvt/fma. VGPR must stay <=64 for 2 blocks/CU.

#define NB    1024
#define NIN   4096
#define NOUT  4096
#define NK    64
#define NTOPK 64

__device__ __forceinline__ int SWZ(int i) { return i ^ ((i >> 3) & 7); }

// ---------------------------------------------------------------- pack ------
// offs8[k8*1024 + b] : uint4 = 8 packed ushorts  (SWZ(idx[b][8k8+j])<<4)
// xs4 [k4*1024 + b]  : float4 = x[b][4k4 .. 4k4+3]
__global__ __launch_bounds__(256) void pack_kernel(const float* __restrict__ x,
                                                   const int* __restrict__ idx,
                                                   uint4* __restrict__ offs8,
                                                   float4* __restrict__ xs4) {
    int tid = blockIdx.x * 256 + threadIdx.x;   // 8192 threads: (b, k8)
    int b  = tid >> 3;
    int k8 = tid & 7;
    const int4* ip = reinterpret_cast<const int4*>(idx + (b << 6) + (k8 << 3));
    const float4* xp = reinterpret_cast<const float4*>(x + (b << 6) + (k8 << 3));
    int4 ia = ip[0], ib = ip[1];
    float4 xa = xp[0], xb = xp[1];

    unsigned o0 = (unsigned)(SWZ(ia.x) << 4), o1 = (unsigned)(SWZ(ia.y) << 4);
    unsigned o2 = (unsigned)(SWZ(ia.z) << 4), o3 = (unsigned)(SWZ(ia.w) << 4);
    unsigned o4 = (unsigned)(SWZ(ib.x) << 4), o5 = (unsigned)(SWZ(ib.y) << 4);
    unsigned o6 = (unsigned)(SWZ(ib.z) << 4), o7 = (unsigned)(SWZ(ib.w) << 4);

    offs8[(k8 << 10) + b] = make_uint4(o0 | (o1 << 16), o2 | (o3 << 16),
                                       o4 | (o5 << 16), o6 | (o7 << 16));
    xs4[((k8 << 1) + 0) * 1024 + b] = xa;
    xs4[((k8 << 1) + 1) * 1024 + b] = xb;
}

// ---------------------------------------------------------------- gemm ------
// Block bo owns W rows [bo*4, bo*4+4) in a swizzled-transposed 64 KB LDS tile
// (conflict-free staging; gathers spread over all 8 bank-groups). 1024 threads,
// 1 b each, 2 blocks/CU (LDS-capped) -> 32 waves/CU iff VGPR <= 64.
__global__ __launch_bounds__(1024, 8) void gemm_kernel(const uint4* __restrict__ offs8,
                                                       const float4* __restrict__ xs4,
                                                       const float* __restrict__ W,
                                                       const float* __restrict__ bias,
                                                       double* __restrict__ C) {
    __shared__ float4 Wt[NIN];   // 64 KB
    const int t  = threadIdx.x;
    const int o0 = blockIdx.x * 4;

    // Conflict-free staging: coalesced row loads, 4x4 register transpose,
    // swizzled b128 writes (lane j -> i=4j+c covers all 8 bank-groups evenly).
    {
        const float4* w0p = reinterpret_cast<const float4*>(W + (size_t)(o0 + 0) * NIN);
        const float4* w1p = reinterpret_cast<const float4*>(W + (size_t)(o0 + 1) * NIN);
        const float4* w2p = reinterpret_cast<const float4*>(W + (size_t)(o0 + 2) * NIN);
        const float4* w3p = reinterpret_cast<const float4*>(W + (size_t)(o0 + 3) * NIN);
        float4 r0 = w0p[t], r1 = w1p[t], r2 = w2p[t], r3 = w3p[t];
        int i0 = t << 2;
        Wt[SWZ(i0 + 0)] = make_float4(r0.x, r1.x, r2.x, r3.x);
        Wt[SWZ(i0 + 1)] = make_float4(r0.y, r1.y, r2.y, r3.y);
        Wt[SWZ(i0 + 2)] = make_float4(r0.z, r1.z, r2.z, r3.z);
        Wt[SWZ(i0 + 3)] = make_float4(r0.w, r1.w, r2.w, r3.w);
    }
    __syncthreads();

    double acc[4];
#pragma unroll
    for (int r = 0; r < 4; ++r) acc[r] = (double)bias[o0 + r];

    const uint4*  op = offs8 + t;   // element k8*1024 + t
    const float4* xp = xs4 + t;     // element k4*1024 + t
    const char*   base = reinterpret_cast<const char*>(Wt);

#define CONSUME(WV, XV)                                                       \
    {                                                                         \
        double xd = (double)(XV);                                             \
        acc[0] += xd * (double)(WV).x; acc[1] += xd * (double)(WV).y;         \
        acc[2] += xd * (double)(WV).z; acc[3] += xd * (double)(WV).w;         \
    }

    // Software pipeline: next-iteration stream loads issue before this
    // iteration's gathers are consumed; gathers batched 4-wide.
    uint4  o8 = op[0];
    float4 xA = xp[0];
    float4 xB = xp[1024];

#pragma unroll 2
    for (int k8 = 0; k8 < NK / 8; ++k8) {
        int kn = (k8 + 1) & 7;               // last iter reloads k8=0 (harmless)
        uint4  o8n = op[kn << 10];
        float4 xAn = xp[kn << 11];
        float4 xBn = xp[(kn << 11) + 1024];

        float4 w0 = *reinterpret_cast<const float4*>(base + (o8.x & 0xFFFFu));
        float4 w1 = *reinterpret_cast<const float4*>(base + (o8.x >> 16));
        float4 w2 = *reinterpret_cast<const float4*>(base + (o8.y & 0xFFFFu));
        float4 w3 = *reinterpret_cast<const float4*>(base + (o8.y >> 16));
        CONSUME(w0, xA.x)
        CONSUME(w1, xA.y)
        CONSUME(w2, xA.z)
        CONSUME(w3, xA.w)

        float4 w4 = *reinterpret_cast<const float4*>(base + (o8.z & 0xFFFFu));
        float4 w5 = *reinterpret_cast<const float4*>(base + (o8.z >> 16));
        float4 w6 = *reinterpret_cast<const float4*>(base + (o8.w & 0xFFFFu));
        float4 w7 = *reinterpret_cast<const float4*>(base + (o8.w >> 16));
        CONSUME(w4, xB.x)
        CONSUME(w5, xB.y)
        CONSUME(w6, xB.z)
        CONSUME(w7, xB.w)

        o8 = o8n; xA = xAn; xB = xBn;
    }
#undef CONSUME

    double2* dst = reinterpret_cast<double2*>(C + (size_t)t * NOUT + o0);
    dst[0] = make_double2(acc[0], acc[1]);
    dst[1] = make_double2(acc[2], acc[3]);
}

// ---------------------------------------------------------------- top-k -----
// Monotone fp32 key: double->float rounding preserves order, so the crossing
// bin over fp32 keys yields a superset of the true top-64; the exact fp64
// bitonic sort of candidates then matches np exactly.
__device__ __forceinline__ unsigned keyf(double d) {
    unsigned u = __float_as_uint((float)d);
    return (u & 0x80000000u) ? ~u : (u | 0x80000000u);
}
// Transposed hist layout: chunk scans (bin = t*16+q) become lane-consecutive.
__device__ __forceinline__ int HADDR(int bin) { return ((bin & 15) << 8) | (bin >> 4); }

__global__ __launch_bounds__(256) void topk_kernel(const double* __restrict__ C,
                                                   float* __restrict__ outv,
                                                   float* __restrict__ outi) {
    __shared__ unsigned hist[4096];    // 16 KB; bin = key>>20 (sign+exp8+mant3)
    __shared__ double   cval[1024];    // 8 KB
    __shared__ int      cidx[1024];    // 4 KB
    __shared__ unsigned part[256];     // 1 KB, chunk sums -> chunk suffixes
    __shared__ int      sBstar;
    __shared__ unsigned sCnt;

    const int t = threadIdx.x;
    const double2* row2 = reinterpret_cast<const double2*>(C + (size_t)blockIdx.x * NOUT);

    double v[16];
#pragma unroll
    for (int q = 0; q < 8; ++q) {
        double2 d = row2[q * 256 + t];
        v[2 * q] = d.x; v[2 * q + 1] = d.y;
    }

    for (int j = t; j < 4096; j += 256) hist[j] = 0u;
    if (t == 0) sCnt = 0u;
    __syncthreads();

#pragma unroll
    for (int q = 0; q < 16; ++q)
        atomicAdd(&hist[HADDR(keyf(v[q]) >> 20)], 1u);
    __syncthreads();

    {
        unsigned s = 0;
#pragma unroll
        for (int q = 0; q < 16; ++q) s += hist[(q << 8) | t];
        part[t] = s;
    }
    __syncthreads();

    if (t < 64) {
        unsigned c0 = part[4 * t + 0], c1 = part[4 * t + 1];
        unsigned c2 = part[4 * t + 2], c3 = part[4 * t + 3];
        unsigned s = c0 + c1 + c2 + c3;
        unsigned suf = s;
        for (int off = 1; off < 64; off <<= 1) {
            unsigned xx = __shfl_down(suf, off);
            if (t + off < 64) suf += xx;
        }
        unsigned below = suf - s;           // sum of chunks > 4t+3
        part[4 * t + 3] = below + c3;
        part[4 * t + 2] = below + c3 + c2;
        part[4 * t + 1] = below + c3 + c2 + c1;
        part[4 * t + 0] = below + s;
    }
    __syncthreads();

    {
        unsigned run = (t < 255) ? part[t + 1] : 0u;
#pragma unroll
        for (int q = 15; q >= 0; --q) {
            unsigned cge = run + hist[(q << 8) | t];
            if (cge >= 64u && run < 64u) sBstar = t * 16 + q;
            run = cge;
        }
    }
    __syncthreads();

    const unsigned Bstar = (unsigned)sBstar;
#pragma unroll
    for (int q = 0; q < 16; ++q) {
        if ((keyf(v[q]) >> 20) >= Bstar) {
            unsigned pos = atomicAdd(&sCnt, 1u);
            if (pos < 1024u) {
                cval[pos] = v[q];
                cidx[pos] = (q >> 1) * 512 + 2 * t + (q & 1);
            }
        }
    }
    __syncthreads();

    int M = (int)sCnt; if (M > 1024) M = 1024;
    int n = 64; while (n < M) n <<= 1;
    for (int j = M + t; j < n; j += 256) { cval[j] = -INFINITY; cidx[j] = 0x7fffffff; }
    __syncthreads();

    for (int kk = 2; kk <= n; kk <<= 1) {
        for (int jj = kk >> 1; jj > 0; jj >>= 1) {
            for (int i = t; i < n; i += 256) {
                int l = i ^ jj;
                if (l > i) {
                    double v1 = cval[i], v2 = cval[l];
                    int    i1 = cidx[i], i2 = cidx[l];
                    bool first = (v1 > v2) || (v1 == v2 && i1 < i2);
                    bool asc   = ((i & kk) == 0);
                    if (first != asc) {
                        cval[i] = v2; cval[l] = v1;
                        cidx[i] = i2; cidx[l] = i1;
                    }
                }
            }
            __syncthreads();
        }
    }

    if (t < 64) {
        outv[(blockIdx.x << 6) + t] = (float)cval[t];
        outi[(blockIdx.x << 6) + t] = (float)cidx[t];
    }
}

// ---------------------------------------------------------------- launch ----
extern "C" void kernel_launch(void* const* d_in, const int* in_sizes, int n_in,
                              void* d_out, int out_size, void* d_ws, size_t ws_size,
                              hipStream_t stream) {
    const float* x    = (const float*)d_in[0];
    const float* W    = (const float*)d_in[1];
    const float* bias = (const float*)d_in[2];
    const int*   idx  = (const int*)d_in[3];

    char*   ws    = (char*)d_ws;
    double* C     = (double*)ws;                                   // 32 MB
    uint4*  offs8 = (uint4*)(ws + (size_t)NB * NOUT * sizeof(double));          // 128 KB
    float4* xs4   = (float4*)(ws + (size_t)NB * NOUT * sizeof(double) + 131072); // 256 KB

    float* outv = (float*)d_out;
    float* outi = outv + NB * NTOPK;

    pack_kernel<<<(NB * 8) / 256, 256, 0, stream>>>(x, idx, offs8, xs4);
    gemm_kernel<<<NOUT / 4, 1024, 0, stream>>>(offs8, xs4, W, bias, C);
    topk_kernel<<<NB, 256, 0, stream>>>(C, outv, outi);
}